// Round 1
// baseline (11165.614 us; speedup 1.0000x reference)
//
#include <hip/hip_runtime.h>
#include <cstddef>

#define DEVFN __device__ __forceinline__

constexpr int N0   = 2712;             // 768+640+704+600
constexpr int MAXL = 768;
constexpr int NBAT = 4;
constexpr int E    = 512;
constexpr int F    = 1024;
constexpr int HID  = 160;
constexpr int WSZ  = 16;               // window length
constexpr int KWIN = WSZ * F;          // 16384
constexpr size_t NOFF = (size_t)-1;

// ---------------- static device scratch pool (offsets in floats) ----------------
constexpr size_t oXF   = 0;
constexpr size_t oKV0  = oXF   + (size_t)N0*E;
constexpr size_t oQ    = oKV0  + (size_t)N0*F;
constexpr size_t oQH   = oQ    + (size_t)N0*E;
constexpr size_t oHU0  = oQH   + (size_t)N0*E;
constexpr size_t oEU0  = oHU0  + (size_t)N0*HID;
constexpr size_t oHD0  = oEU0  + (size_t)N0;
constexpr size_t oDAT1 = oHD0  + (size_t)N0*HID;
constexpr size_t oHU1  = oDAT1 + (size_t)N0*F;
constexpr size_t oEU1  = oHU1  + (size_t)N0*HID;
constexpr size_t oHD1  = oEU1  + (size_t)N0;
constexpr size_t oDAT2 = oHD1  + (size_t)N0*HID;
constexpr size_t oKH0  = oDAT2 + (size_t)N0*F;
constexpr size_t oVH0  = oKH0  + (size_t)N0*E;
constexpr size_t oBH0K = oVH0  + (size_t)N0*E;
constexpr size_t oBH0V = oBH0K + (size_t)15*E;
constexpr size_t oDH1K = oBH0V + (size_t)15*E;
constexpr size_t oDH1V = oDH1K + (size_t)N0*E;
constexpr size_t oDH2K = oDH1V + (size_t)N0*E;
constexpr size_t oDH2V = oDH2K + (size_t)N0*E;
constexpr size_t oCTX  = oDH2V + (size_t)N0*E;
constexpr size_t oY1   = oCTX  + (size_t)N0*E;
constexpr size_t oY2   = oY1   + (size_t)N0*E;
constexpr size_t oEUS0 = oY2   + (size_t)N0*E;
constexpr size_t oEUS1 = oEUS0 + (size_t)N0;
constexpr size_t oSEL0 = oEUS1 + (size_t)N0;
constexpr size_t oTM0  = oSEL0 + (size_t)N0;
constexpr size_t oSEL1 = oTM0  + (size_t)N0;
constexpr size_t oTM1  = oSEL1 + (size_t)N0;
constexpr size_t oB0   = oTM1  + (size_t)N0;
constexpr size_t oB1   = oB0   + 8;
constexpr size_t oB2   = oB1   + 8;
constexpr size_t oEND  = oB2   + 8;

__device__ float g_pool[oEND];   // ~107 MB, allocated at module load (graph-capture safe)

DEVFN float geluf(float x) {
    return 0.5f * x * (1.0f + erff(x / 1.41421356237309504880f));
}

// ---------------- tiny init: level-0 segment bounds ----------------
__global__ void k_init() {
    if (threadIdx.x == 0) {
        int* b = (int*)(g_pool + oB0);
        b[0] = 0; b[1] = 768; b[2] = 1408; b[3] = 2112; b[4] = N0;
    }
}

// ---------------- x (B,768,E) -> x_flat (N0,E) ----------------
__global__ __launch_bounds__(256) void k_xflat(const float* __restrict__ x) {
    int idx = blockIdx.x * 256 + threadIdx.x;
    if (idx >= N0 * E) return;
    int d = idx & (E - 1);
    int g = idx >> 9;
    int s = (g >= 768) + (g >= 1408) + (g >= 2112);
    const int st[4] = {0, 768, 1408, 2112};
    int qp = g - st[s];
    g_pool[oXF + idx] = x[((size_t)s * MAXL + qp) * E + d];
}

// ---------------- generic f32 GEMM: C = A@B + bias ----------------
// plain mode: A[r*lda + k]  (A = Aext if non-null else pool+Aoff)
// windowed mode: A[r][k] = window element j=k>>10,f=k&1023 over src rows /
//                buffer rows, segment geometry from bounds; optional rowmap.
template<bool WINDOWED>
__global__ __launch_bounds__(256) void k_gemm(
    const float* __restrict__ Aext, size_t Aoff, int lda,
    size_t srcOff, const float* __restrict__ buf, size_t rowmapOff, size_t boundsOff,
    const float* __restrict__ B, const float* __restrict__ bias,
    size_t Coff, int M, size_t mdevOff, int K, int N)
{
    int mval = (mdevOff == NOFF) ? M : *(const int*)(g_pool + mdevOff);
    int row0 = blockIdx.x * 64, col0 = blockIdx.y * 64;
    if (row0 >= mval) return;

    const float* A   = Aext ? Aext : (g_pool + Aoff);
    const float* src = g_pool + srcOff;
    const int* rowmap = (rowmapOff == NOFF) ? nullptr : (const int*)(g_pool + rowmapOff);
    float* C = g_pool + Coff;

    __shared__ __align__(16) float As[32][68];
    __shared__ __align__(16) float Bs[32][64];
    __shared__ int sRow[64], sQp[64];

    int tid = threadIdx.x;
    if (WINDOWED) {
        if (tid < 64) {
            int r = row0 + tid;
            int g = 0, qp = 0;
            if (r < mval) {
                const int* bounds = (const int*)(g_pool + boundsOff);
                g = rowmap ? rowmap[r] : r;
                int b1 = bounds[1], b2 = bounds[2], b3 = bounds[3];
                int s = (g >= b1) + (g >= b2) + (g >= b3);
                int st = (s == 0) ? 0 : ((s == 1) ? b1 : ((s == 2) ? b2 : b3));
                qp = g - st;
            }
            sRow[tid] = g; sQp[tid] = qp;
        }
        __syncthreads();
    }

    float acc[4][4] = {};
    int tx = tid & 15, ty = tid >> 4;

    for (int k0 = 0; k0 < K; k0 += 32) {
        #pragma unroll
        for (int l = 0; l < 8; ++l) {
            int idx = tid + l * 256;
            int kk = idx & 31, m = idx >> 5;
            int r = row0 + m;
            float v = 0.0f;
            if (r < mval) {
                int k = k0 + kk;
                if (WINDOWED) {
                    int j = k >> 10, f = k & 1023;
                    int sp = sQp[m] - j;
                    v = (sp >= 0) ? src[(size_t)(sRow[m] - j) * F + f]
                                  : buf[(size_t)(15 + sp) * F + f];
                } else {
                    v = A[(size_t)r * lda + k];
                }
            }
            As[kk][m] = v;
        }
        #pragma unroll
        for (int l = 0; l < 8; ++l) {
            int idx = tid + l * 256;
            int n = idx & 63, kk = idx >> 6;
            int col = col0 + n;
            float v = 0.0f;
            if (col < N) v = B[(size_t)(k0 + kk) * N + col];
            Bs[kk][n] = v;
        }
        __syncthreads();
        #pragma unroll
        for (int kk = 0; kk < 32; ++kk) {
            float4 a4 = *(const float4*)&As[kk][ty * 4];
            float4 b4 = *(const float4*)&Bs[kk][tx * 4];
            float av[4] = {a4.x, a4.y, a4.z, a4.w};
            float bv[4] = {b4.x, b4.y, b4.z, b4.w};
            #pragma unroll
            for (int i = 0; i < 4; ++i)
                #pragma unroll
                for (int jn = 0; jn < 4; ++jn)
                    acc[i][jn] = fmaf(av[i], bv[jn], acc[i][jn]);
        }
        __syncthreads();
    }

    #pragma unroll
    for (int i = 0; i < 4; ++i) {
        int r = row0 + ty * 4 + i;
        if (r >= mval) continue;
        #pragma unroll
        for (int jn = 0; jn < 4; ++jn) {
            int col = col0 + tx * 4 + jn;
            if (col < N)
                C[(size_t)r * N + col] = acc[i][jn] + (bias ? bias[col] : 0.0f);
        }
    }
}

// ---------------- eu = elu(gelu(h)@w2 + b2) + 1 ----------------
__global__ __launch_bounds__(64) void k_eu(
    size_t hOff, const float* __restrict__ w2, const float* __restrict__ b2,
    size_t euOff, size_t mdevOff, int M)
{
    int row = blockIdx.x;
    int mval = (mdevOff == NOFF) ? M : *(const int*)(g_pool + mdevOff);
    if (row >= mval) return;
    const float* h = g_pool + hOff;
    int lane = threadIdx.x;
    float s = 0.0f;
    for (int k = lane; k < HID; k += 64)
        s += geluf(h[(size_t)row * HID + k]) * w2[k];
    #pragma unroll
    for (int o = 32; o; o >>= 1) s += __shfl_xor(s, o, 64);
    if (lane == 0) {
        float v = s + b2[0];
        v = (v > 0.0f) ? v : expm1f(v);
        g_pool[euOff + row] = v + 1.0f;
    }
}

// ---------------- sequential selection scan (matches jnp.cumsum order) ----------------
__global__ __launch_bounds__(256) void k_select(
    size_t euOff, size_t boundsOff, int win,
    size_t selOff, size_t tmOff, size_t euSelOff, size_t boundsNextOff)
{
    __shared__ float se[N0];
    const int* bounds = (const int*)(g_pool + boundsOff);
    int N = bounds[4];
    for (int i = threadIdx.x; i < N; i += 256) se[i] = g_pool[euOff + i];
    __syncthreads();
    if (threadIdx.x != 0) return;

    int b[5];
    for (int i = 0; i < 5; ++i) b[i] = bounds[i];

    float end_u[NBAT];
    {
        float run = 0.0f; int seg = 0;
        for (int g = 0; g < N; ++g) {
            run += se[g];
            if (g == b[seg + 1] - 1) { end_u[seg] = run; ++seg; }
        }
    }
    float sample_u[NBAT - 1];
    sample_u[0] = end_u[0];                       // note: reference's exact (odd) formula
    for (int i = 1; i < NBAT - 1; ++i) sample_u[i] = end_u[i + 1] - end_u[i];

    int* sel = (int*)(g_pool + selOff);
    int* tm  = (int*)(g_pool + tmOff);
    float* eus = g_pool + euSelOff;
    int* bn  = (int*)(g_pool + boundsNextOff);

    float run = 0.0f, cz = 0.0f;
    int csel = 0, csel0 = 0, cnt = 0, seg = 0;
    int ec[NBAT];
    for (int g = 0; g < N; ++g) {
        while (g >= b[seg + 1]) ++seg;
        if (g == b[seg] && seg > 0) cz += sample_u[seg - 1];
        run += se[g];
        float r2 = run - cz;
        int qp1 = g - b[seg] + 1;                 // idxs (exact int)
        bool seld = (se[g] > r2 / (float)qp1) || (qp1 <= win);
        if (seld) { sel[cnt] = g; eus[cnt] = se[g]; ++cnt; }
        csel += seld ? 1 : 0;
        if (g == 0) csel0 = csel;
        tm[g] = csel - csel0;
        if (g == b[seg + 1] - 1) ec[seg] = csel;
    }
    bn[0] = 0; bn[1] = ec[0]; bn[2] = ec[1]; bn[3] = ec[2]; bn[4] = ec[3];
}

// ---------------- r = softmax(gelu(h)@w2 + b2); dat[i] = sum_j r[j]*window(g,j) ----------------
__global__ __launch_bounds__(256) void k_rdat(
    size_t hOff, const float* __restrict__ w2, const float* __restrict__ b2,
    size_t selOff, size_t mdevOff,
    size_t srcOff, const float* __restrict__ buf, size_t boundsOff,
    size_t datOff)
{
    int i = blockIdx.x;
    if (i >= *(const int*)(g_pool + mdevOff)) return;
    const float* h = g_pool + hOff;
    const float* src = g_pool + srcOff;
    const int* bounds = (const int*)(g_pool + boundsOff);
    const int* sel = (const int*)(g_pool + selOff);
    float* dat = g_pool + datOff;

    __shared__ float gh[HID];
    __shared__ float sv[WSZ];
    __shared__ float r[WSZ];
    int tid = threadIdx.x;
    for (int k = tid; k < HID; k += 256) gh[k] = geluf(h[(size_t)i * HID + k]);
    __syncthreads();
    if (tid < WSZ) {
        float acc = 0.0f;
        for (int k = 0; k < HID; ++k) acc += gh[k] * w2[k * WSZ + tid];
        sv[tid] = acc + b2[tid];
    }
    __syncthreads();
    if (tid == 0) {
        float m = sv[0];
        for (int t = 1; t < WSZ; ++t) m = fmaxf(m, sv[t]);
        float sum = 0.0f;
        for (int t = 0; t < WSZ; ++t) { float e = expf(sv[t] - m); r[t] = e; sum += e; }
        for (int t = 0; t < WSZ; ++t) r[t] = r[t] / sum;
    }
    __syncthreads();
    int g = sel[i];
    int b1 = bounds[1], b2i = bounds[2], b3 = bounds[3];
    int s = (g >= b1) + (g >= b2i) + (g >= b3);
    int st = (s == 0) ? 0 : ((s == 1) ? b1 : ((s == 2) ? b2i : b3));
    int qp = g - st;
    for (int f = tid; f < F; f += 256) {
        float acc = 0.0f;
        for (int j = 0; j < WSZ; ++j) {
            int sp = qp - j;
            float v = (sp >= 0) ? src[(size_t)(g - j) * F + f]
                                : buf[(size_t)(15 + sp) * F + f];
            acc = fmaf(r[j], v, acc);
        }
        dat[(size_t)i * F + f] = acc;
    }
}

// ---------------- fused attention over 48 gathered kv slots ----------------
__global__ __launch_bounds__(512) void k_attn(
    const float* __restrict__ bk, const float* __restrict__ bv)
{
    int g = blockIdx.x;
    const float* qh   = g_pool + oQH;
    const float* KH0  = g_pool + oKH0;
    const float* VH0  = g_pool + oVH0;
    const float* BH0k = g_pool + oBH0K;
    const float* BH0v = g_pool + oBH0V;
    const float* DH1k = g_pool + oDH1K;
    const float* DH1v = g_pool + oDH1V;
    const float* DH2k = g_pool + oDH2K;
    const float* DH2v = g_pool + oDH2V;
    const float* eus0 = g_pool + oEUS0;
    const float* eus1 = g_pool + oEUS1;
    const int* tm0 = (const int*)(g_pool + oTM0);
    const int* tm1 = (const int*)(g_pool + oTM1);
    const int* bounds1 = (const int*)(g_pool + oB1);
    const int* bounds2 = (const int*)(g_pool + oB2);

    __shared__ const float* sK[48];
    __shared__ const float* sV[48];
    __shared__ float sScale[48];
    __shared__ float sQ[E], sBk[E], sBv[E];
    __shared__ float sc[48][8];

    int tid = threadIdx.x;
    sQ[tid]  = qh[(size_t)g * E + tid];
    sBk[tid] = bk[tid];
    sBv[tid] = bv[tid];

    if (tid < 48) {
        int s = tid;
        const float *pK = nullptr, *pV = nullptr;
        float scl = 0.0f;
        if (s < 16) {
            int s0 = (g >= 768) + (g >= 1408) + (g >= 2112);
            const int st0[4] = {0, 768, 1408, 2112};
            int sp = (g - st0[s0]) - s;
            if (sp >= 0) { pK = KH0 + (size_t)(g - s) * E; pV = VH0 + (size_t)(g - s) * E; }
            else         { pK = BH0k + (size_t)(15 + sp) * E; pV = BH0v + (size_t)(15 + sp) * E; }
            scl = 1.0f;
        } else if (s < 32) {
            int j = s - 16;
            int i1 = tm0[g];
            int b1 = bounds1[1], b2 = bounds1[2], b3 = bounds1[3];
            int sg = (i1 >= b1) + (i1 >= b2) + (i1 >= b3);
            int st = (sg == 0) ? 0 : ((sg == 1) ? b1 : ((sg == 2) ? b2 : b3));
            int sp = (i1 - st) - j;
            if (sp >= 0) { pK = DH1k + (size_t)(i1 - j) * E; pV = DH1v + (size_t)(i1 - j) * E; scl = eus0[i1 - j]; }
        } else {
            int j = s - 32;
            int i1 = tm0[g];
            int i2 = tm1[i1];
            int b1 = bounds2[1], b2 = bounds2[2], b3 = bounds2[3];
            int sg = (i2 >= b1) + (i2 >= b2) + (i2 >= b3);
            int st = (sg == 0) ? 0 : ((sg == 1) ? b1 : ((sg == 2) ? b2 : b3));
            int sp = (i2 - st) - j;
            if (sp >= 0) { pK = DH2k + (size_t)(i2 - j) * E; pV = DH2v + (size_t)(i2 - j) * E; scl = eus1[i2 - j]; }
        }
        sK[s] = pK; sV[s] = pV; sScale[s] = scl;
    }
    __syncthreads();

    if (tid < 384) {
        int s = tid >> 3, h = tid & 7;
        const float* bp = sK[s];
        float scl = sScale[s];
        float acc = 0.0f;
        int d0 = h * 64;
        if (s < 16) {
            for (int d = 0; d < 64; ++d) acc += sQ[d0 + d] * bp[d0 + d];  // bias baked in
        } else {
            for (int d = 0; d < 64; ++d) {
                float kvv = sBk[d0 + d] + (bp ? scl * bp[d0 + d] : 0.0f);
                acc += sQ[d0 + d] * kvv;
            }
        }
        sc[s][h] = acc * 0.125f;   // / sqrt(64)
    }
    __syncthreads();

    if (tid < 8) {
        int h = tid;
        float m = sc[0][h];
        for (int s = 1; s < 48; ++s) m = fmaxf(m, sc[s][h]);
        float sum = 0.0f;
        for (int s = 0; s < 48; ++s) { float e = expf(sc[s][h] - m); sc[s][h] = e; sum += e; }
        for (int s = 0; s < 48; ++s) sc[s][h] = sc[s][h] / sum;
    }
    __syncthreads();

    {
        int d = tid, h = d >> 6;
        float acc = 0.0f;
        for (int s = 0; s < 48; ++s) {
            const float* bp = sV[s];
            float vv;
            if (s < 16) vv = bp[d];
            else        vv = sBv[d] + (bp ? sScale[s] * bp[d] : 0.0f);
            acc = fmaf(sc[s][h], vv, acc);
        }
        g_pool[oCTX + (size_t)g * E + d] = acc;
    }
}

// ---------------- y2 -> out (B, 768, E) with zero padding ----------------
__global__ __launch_bounds__(256) void k_scatter(float* __restrict__ out) {
    int idx = blockIdx.x * 256 + threadIdx.x;
    if (idx >= NBAT * MAXL * E) return;
    int d = idx & (E - 1);
    int rest = idx >> 9;
    int p = rest % MAXL, bb = rest / MAXL;
    const int st[4] = {0, 768, 1408, 2112};
    const int ln[4] = {768, 640, 704, 600};
    out[idx] = (p < ln[bb]) ? g_pool[oY2 + (size_t)(st[bb] + p) * E + d] : 0.0f;
}

// ================================================================================
extern "C" void kernel_launch(void* const* d_in, const int* in_sizes, int n_in,
                              void* d_out, int out_size, void* d_ws, size_t ws_size,
                              hipStream_t stream)
{
    (void)in_sizes; (void)n_in; (void)d_ws; (void)ws_size; (void)out_size;

    const float* x      = (const float*)d_in[0];
    const float* kv_w   = (const float*)d_in[2];
    const float* kv_b   = (const float*)d_in[3];
    const float* q_w    = (const float*)d_in[4];
    const float* q_b    = (const float*)d_in[5];
    const float* proj_w = (const float*)d_in[6];
    const float* proj_b = (const float*)d_in[7];
    const float* buf0   = (const float*)d_in[8];
    const float* buf1   = (const float*)d_in[9];
    /* buf2 (d_in[10]) never reaches the output: win2 buffer slots are zeroed by util1 */
    const float* d0_w1  = (const float*)d_in[11];
    const float* d0_b1  = (const float*)d_in[12];
    const float* d0_w2  = (const float*)d_in[13];
    const float* d0_b2  = (const float*)d_in[14];
    const float* u0_w1  = (const float*)d_in[15];
    const float* u0_b1  = (const float*)d_in[16];
    const float* u0_w2  = (const float*)d_in[17];
    const float* u0_b2  = (const float*)d_in[18];
    const float* d1_w1  = (const float*)d_in[19];
    const float* d1_b1  = (const float*)d_in[20];
    const float* d1_w2  = (const float*)d_in[21];
    const float* d1_b2  = (const float*)d_in[22];
    const float* u1_w1  = (const float*)d_in[23];
    const float* u1_b1  = (const float*)d_in[24];
    const float* u1_w2  = (const float*)d_in[25];
    const float* u1_b2  = (const float*)d_in[26];
    const float* wq     = (const float*)d_in[27];
    const float* bq     = (const float*)d_in[28];
    const float* wk     = (const float*)d_in[29];
    const float* bk     = (const float*)d_in[30];
    const float* wv     = (const float*)d_in[31];
    const float* bv     = (const float*)d_in[32];
    const float* out_w  = (const float*)d_in[33];
    const float* out_b  = (const float*)d_in[34];

    auto cdiv = [](int a, int b) { return (a + b - 1) / b; };
    auto G = [&](int M, int N) { return dim3(cdiv(M, 64), cdiv(N, 64)); };

    k_init<<<1, 64, 0, stream>>>();
    k_xflat<<<cdiv(N0 * E, 256), 256, 0, stream>>>(x);

    // kv0 = x_flat @ kv_w + kv_b
    k_gemm<false><<<G(N0, F), 256, 0, stream>>>(nullptr, oXF, E, 0, nullptr, NOFF, 0,
        kv_w, kv_b, oKV0, N0, NOFF, E, F);
    // q = x_flat @ q_w + q_b ; qh = q @ wq + bq
    k_gemm<false><<<G(N0, E), 256, 0, stream>>>(nullptr, oXF, E, 0, nullptr, NOFF, 0,
        q_w, q_b, oQ, N0, NOFF, E, E);
    k_gemm<false><<<G(N0, E), 256, 0, stream>>>(nullptr, oQ, E, 0, nullptr, NOFF, 0,
        wq, bq, oQH, N0, NOFF, E, E);

    // ---- level 0: u0 windowed MLP -> eu0 -> selection ----
    k_gemm<true><<<G(N0, HID), 256, 0, stream>>>(nullptr, 0, 0, oKV0, buf0, NOFF, oB0,
        u0_w1, u0_b1, oHU0, N0, NOFF, KWIN, HID);
    k_eu<<<N0, 64, 0, stream>>>(oHU0, u0_w2, u0_b2, oEU0, NOFF, N0);
    k_select<<<1, 256, 0, stream>>>(oEU0, oB0, WSZ, oSEL0, oTM0, oEUS0, oB1);

    // ---- d0 windowed MLP on selected rows -> dat1 ----
    k_gemm<true><<<G(N0, HID), 256, 0, stream>>>(nullptr, 0, 0, oKV0, buf0, oSEL0, oB0,
        d0_w1, d0_b1, oHD0, N0, oB1 + 4, KWIN, HID);
    k_rdat<<<N0, 256, 0, stream>>>(oHD0, d0_w2, d0_b2, oSEL0, oB1 + 4, oKV0, buf0, oB0, oDAT1);

    // ---- level 1: u1 -> eu1 -> selection ----
    k_gemm<true><<<G(N0, HID), 256, 0, stream>>>(nullptr, 0, 0, oDAT1, buf1, NOFF, oB1,
        u1_w1, u1_b1, oHU1, N0, oB1 + 4, KWIN, HID);
    k_eu<<<N0, 64, 0, stream>>>(oHU1, u1_w2, u1_b2, oEU1, oB1 + 4, N0);
    k_select<<<1, 256, 0, stream>>>(oEU1, oB1, WSZ, oSEL1, oTM1, oEUS1, oB2);

    // ---- d1 on selected level-1 rows -> dat2 ----
    k_gemm<true><<<G(N0, HID), 256, 0, stream>>>(nullptr, 0, 0, oDAT1, buf1, oSEL1, oB1,
        d1_w1, d1_b1, oHD1, N0, oB2 + 4, KWIN, HID);
    k_rdat<<<N0, 256, 0, stream>>>(oHD1, d1_w2, d1_b2, oSEL1, oB2 + 4, oDAT1, buf1, oB1, oDAT2);

    // ---- attention prep: project every distinct kv row once (linearity) ----
    k_gemm<false><<<G(N0, E), 256, 0, stream>>>(nullptr, oKV0, F, 0, nullptr, NOFF, 0,
        wk, bk, oKH0, N0, NOFF, E, E);
    k_gemm<false><<<G(N0, E), 256, 0, stream>>>(nullptr, oKV0 + E, F, 0, nullptr, NOFF, 0,
        wv, bv, oVH0, N0, NOFF, E, E);
    k_gemm<false><<<G(15, E), 256, 0, stream>>>(buf0, 0, F, 0, nullptr, NOFF, 0,
        wk, bk, oBH0K, 15, NOFF, E, E);
    k_gemm<false><<<G(15, E), 256, 0, stream>>>(buf0 + E, 0, F, 0, nullptr, NOFF, 0,
        wv, bv, oBH0V, 15, NOFF, E, E);
    k_gemm<false><<<G(N0, E), 256, 0, stream>>>(nullptr, oDAT1, F, 0, nullptr, NOFF, 0,
        wk, nullptr, oDH1K, N0, oB1 + 4, E, E);
    k_gemm<false><<<G(N0, E), 256, 0, stream>>>(nullptr, oDAT1 + E, F, 0, nullptr, NOFF, 0,
        wv, nullptr, oDH1V, N0, oB1 + 4, E, E);
    k_gemm<false><<<G(N0, E), 256, 0, stream>>>(nullptr, oDAT2, F, 0, nullptr, NOFF, 0,
        wk, nullptr, oDH2K, N0, oB2 + 4, E, E);
    k_gemm<false><<<G(N0, E), 256, 0, stream>>>(nullptr, oDAT2 + E, F, 0, nullptr, NOFF, 0,
        wv, nullptr, oDH2V, N0, oB2 + 4, E, E);

    // ---- fused attention + output projections + scatter ----
    k_attn<<<N0, 512, 0, stream>>>(bk, bv);
    k_gemm<false><<<G(N0, E), 256, 0, stream>>>(nullptr, oCTX, E, 0, nullptr, NOFF, 0,
        out_w, out_b, oY1, N0, NOFF, E, E);
    k_gemm<false><<<G(N0, E), 256, 0, stream>>>(nullptr, oY1, E, 0, nullptr, NOFF, 0,
        proj_w, proj_b, oY2, N0, NOFF, E, E);
    k_scatter<<<cdiv(NBAT * MAXL * E, 256), 256, 0, stream>>>((float*)d_out);
}

// Round 2
// 3442.028 us; speedup vs baseline: 3.2439x; 3.2439x over previous
//
#include <hip/hip_runtime.h>
#include <cstddef>

#define DEVFN __device__ __forceinline__

constexpr int N0   = 2712;             // 768+640+704+600
constexpr int MAXL = 768;
constexpr int NBAT = 4;
constexpr int E    = 512;
constexpr int F    = 1024;
constexpr int HID  = 160;
constexpr int WSZ  = 16;               // window length
constexpr int NSPLIT = 16;             // split-K factor = window size
constexpr size_t NOFF = (size_t)-1;

// ---------------- static device scratch pool (offsets in floats) ----------------
constexpr size_t oXF   = 0;
constexpr size_t oKV0  = oXF   + (size_t)N0*E;
constexpr size_t oQ    = oKV0  + (size_t)N0*F;
constexpr size_t oQH   = oQ    + (size_t)N0*E;
constexpr size_t oHU0  = oQH   + (size_t)N0*E;
constexpr size_t oEU0  = oHU0  + (size_t)N0*HID;
constexpr size_t oHD0  = oEU0  + (size_t)N0;
constexpr size_t oDAT1 = oHD0  + (size_t)N0*HID;
constexpr size_t oHU1  = oDAT1 + (size_t)N0*F;
constexpr size_t oEU1  = oHU1  + (size_t)N0*HID;
constexpr size_t oHD1  = oEU1  + (size_t)N0;
constexpr size_t oDAT2 = oHD1  + (size_t)N0*HID;
constexpr size_t oKH0  = oDAT2 + (size_t)N0*F;
constexpr size_t oVH0  = oKH0  + (size_t)N0*E;
constexpr size_t oBH0K = oVH0  + (size_t)N0*E;
constexpr size_t oBH0V = oBH0K + (size_t)15*E;
constexpr size_t oDH1K = oBH0V + (size_t)15*E;
constexpr size_t oDH1V = oDH1K + (size_t)N0*E;
constexpr size_t oDH2K = oDH1V + (size_t)N0*E;
constexpr size_t oDH2V = oDH2K + (size_t)N0*E;
constexpr size_t oCTX  = oDH2V + (size_t)N0*E;
constexpr size_t oY1   = oCTX  + (size_t)N0*E;
constexpr size_t oY2   = oY1   + (size_t)N0*E;
constexpr size_t oEUS0 = oY2   + (size_t)N0*E;
constexpr size_t oEUS1 = oEUS0 + (size_t)N0;
constexpr size_t oSEL0 = oEUS1 + (size_t)N0;
constexpr size_t oTM0  = oSEL0 + (size_t)N0;
constexpr size_t oSEL1 = oTM0  + (size_t)N0;
constexpr size_t oTM1  = oSEL1 + (size_t)N0;
constexpr size_t oB0   = oTM1  + (size_t)N0;
constexpr size_t oB1   = oB0   + 8;
constexpr size_t oB2   = oB1   + 8;
constexpr size_t oPART = oB2   + 8;                          // split-K partials
constexpr size_t oEND  = oPART + (size_t)NSPLIT*N0*HID;

__device__ float g_pool[oEND];   // ~135 MB, allocated at module load (graph-capture safe)

DEVFN float geluf(float x) {
    return 0.5f * x * (1.0f + erff(x / 1.41421356237309504880f));
}

// ---------------- tiny init: level-0 segment bounds ----------------
__global__ void k_init() {
    if (threadIdx.x == 0) {
        int* b = (int*)(g_pool + oB0);
        b[0] = 0; b[1] = 768; b[2] = 1408; b[3] = 2112; b[4] = N0;
    }
}

// ---------------- x (B,768,E) -> x_flat (N0,E) ----------------
__global__ __launch_bounds__(256) void k_xflat(const float* __restrict__ x) {
    int idx = blockIdx.x * 256 + threadIdx.x;
    if (idx >= N0 * E) return;
    int d = idx & (E - 1);
    int g = idx >> 9;
    int s = (g >= 768) + (g >= 1408) + (g >= 2112);
    const int st[4] = {0, 768, 1408, 2112};
    int qp = g - st[s];
    g_pool[oXF + idx] = x[((size_t)s * MAXL + qp) * E + d];
}

// ---------------- plain f32 GEMM: C = A@B + bias ----------------
__global__ __launch_bounds__(256) void k_pgemm(
    const float* __restrict__ Aext, size_t Aoff, int lda,
    const float* __restrict__ B, const float* __restrict__ bias,
    size_t Coff, int M, size_t mdevOff, int K, int N)
{
    int mval = (mdevOff == NOFF) ? M : *(const int*)(g_pool + mdevOff);
    int row0 = blockIdx.x * 64, col0 = blockIdx.y * 64;
    if (row0 >= mval) return;

    const float* A = Aext ? Aext : (g_pool + Aoff);
    float* C = g_pool + Coff;

    __shared__ __align__(16) float As[32][68];
    __shared__ __align__(16) float Bs[32][64];

    int tid = threadIdx.x;
    float acc[4][4] = {};
    int tx = tid & 15, ty = tid >> 4;

    for (int k0 = 0; k0 < K; k0 += 32) {
        #pragma unroll
        for (int l = 0; l < 8; ++l) {
            int idx = tid + l * 256;
            int kk = idx & 31, m = idx >> 5;
            int r = row0 + m;
            float v = 0.0f;
            if (r < mval) v = A[(size_t)r * lda + k0 + kk];
            As[kk][m] = v;
        }
        #pragma unroll
        for (int l = 0; l < 8; ++l) {
            int idx = tid + l * 256;
            int n = idx & 63, kk = idx >> 6;
            int col = col0 + n;
            float v = 0.0f;
            if (col < N) v = B[(size_t)(k0 + kk) * N + col];
            Bs[kk][n] = v;
        }
        __syncthreads();
        #pragma unroll
        for (int kk = 0; kk < 32; ++kk) {
            float4 a4 = *(const float4*)&As[kk][ty * 4];
            float4 b4 = *(const float4*)&Bs[kk][tx * 4];
            float av[4] = {a4.x, a4.y, a4.z, a4.w};
            float bv[4] = {b4.x, b4.y, b4.z, b4.w};
            #pragma unroll
            for (int i = 0; i < 4; ++i)
                #pragma unroll
                for (int jn = 0; jn < 4; ++jn)
                    acc[i][jn] = fmaf(av[i], bv[jn], acc[i][jn]);
        }
        __syncthreads();
    }

    #pragma unroll
    for (int i = 0; i < 4; ++i) {
        int r = row0 + ty * 4 + i;
        if (r >= mval) continue;
        #pragma unroll
        for (int jn = 0; jn < 4; ++jn) {
            int col = col0 + tx * 4 + jn;
            if (col < N)
                C[(size_t)r * N + col] = acc[i][jn] + (bias ? bias[col] : 0.0f);
        }
    }
}

// ---------------- windowed GEMM, split-K over window index j ----------------
// part[z][r][n] = sum_f window(r, j=z, f) * W1[(z*F+f)][n]
__global__ __launch_bounds__(256) void k_wgemm(
    size_t srcOff, const float* __restrict__ buf, size_t rowmapOff, size_t boundsOff,
    const float* __restrict__ B, int M, size_t mdevOff)
{
    int mval = (mdevOff == NOFF) ? M : *(const int*)(g_pool + mdevOff);
    int row0 = blockIdx.x * 64, col0 = blockIdx.y * 64;
    int j = blockIdx.z;
    if (row0 >= mval) return;

    const float* src = g_pool + srcOff;
    const int* rowmap = (rowmapOff == NOFF) ? nullptr : (const int*)(g_pool + rowmapOff);
    float* part = g_pool + oPART + (size_t)j * N0 * HID;

    __shared__ __align__(16) float As[32][68];
    __shared__ __align__(16) float Bs[32][64];
    __shared__ const float* sPtr[64];

    int tid = threadIdx.x;
    if (tid < 64) {
        int r = row0 + tid;
        const float* p = src;                  // dummy-safe for r >= mval
        if (r < mval) {
            const int* bounds = (const int*)(g_pool + boundsOff);
            int g = rowmap ? rowmap[r] : r;
            int b1 = bounds[1], b2 = bounds[2], b3 = bounds[3];
            int s = (g >= b1) + (g >= b2) + (g >= b3);
            int st = (s == 0) ? 0 : ((s == 1) ? b1 : ((s == 2) ? b2 : b3));
            int sp = (g - st) - j;
            p = (sp >= 0) ? (src + (size_t)(g - j) * F)
                          : (buf + (size_t)(15 + sp) * F);
        }
        sPtr[tid] = p;
    }
    __syncthreads();

    float acc[4][4] = {};
    int tx = tid & 15, ty = tid >> 4;
    const float* Bj = B + (size_t)j * F * HID;

    for (int f0 = 0; f0 < F; f0 += 32) {
        #pragma unroll
        for (int l = 0; l < 8; ++l) {
            int idx = tid + l * 256;
            int kk = idx & 31, m = idx >> 5;
            As[kk][m] = sPtr[m][f0 + kk];
        }
        #pragma unroll
        for (int l = 0; l < 8; ++l) {
            int idx = tid + l * 256;
            int n = idx & 63, kk = idx >> 6;
            int col = col0 + n;
            float v = 0.0f;
            if (col < HID) v = Bj[(size_t)(f0 + kk) * HID + col];
            Bs[kk][n] = v;
        }
        __syncthreads();
        #pragma unroll
        for (int kk = 0; kk < 32; ++kk) {
            float4 a4 = *(const float4*)&As[kk][ty * 4];
            float4 b4 = *(const float4*)&Bs[kk][tx * 4];
            float av[4] = {a4.x, a4.y, a4.z, a4.w};
            float bv[4] = {b4.x, b4.y, b4.z, b4.w};
            #pragma unroll
            for (int i = 0; i < 4; ++i)
                #pragma unroll
                for (int jn = 0; jn < 4; ++jn)
                    acc[i][jn] = fmaf(av[i], bv[jn], acc[i][jn]);
        }
        __syncthreads();
    }

    #pragma unroll
    for (int i = 0; i < 4; ++i) {
        int r = row0 + ty * 4 + i;
        if (r >= mval) continue;
        #pragma unroll
        for (int jn = 0; jn < 4; ++jn) {
            int col = col0 + tx * 4 + jn;
            if (col < HID)
                part[(size_t)r * HID + col] = acc[i][jn];
        }
    }
}

// ---------------- reduce split-K partials (+bias), in fixed j order ----------------
__global__ __launch_bounds__(256) void k_wreduce(
    const float* __restrict__ bias, size_t outOff, size_t mdevOff, int M)
{
    int mval = (mdevOff == NOFF) ? M : *(const int*)(g_pool + mdevOff);
    int idx = blockIdx.x * 256 + threadIdx.x;
    if (idx >= mval * HID) return;
    int n = idx % HID;
    float s = bias[n];
    const float* part = g_pool + oPART;
    #pragma unroll
    for (int z = 0; z < NSPLIT; ++z)
        s += part[(size_t)z * N0 * HID + idx];
    g_pool[outOff + idx] = s;
}

// ---------------- eu = elu(gelu(h)@w2 + b2) + 1 ----------------
__global__ __launch_bounds__(64) void k_eu(
    size_t hOff, const float* __restrict__ w2, const float* __restrict__ b2,
    size_t euOff, size_t mdevOff, int M)
{
    int row = blockIdx.x;
    int mval = (mdevOff == NOFF) ? M : *(const int*)(g_pool + mdevOff);
    if (row >= mval) return;
    const float* h = g_pool + hOff;
    int lane = threadIdx.x;
    float s = 0.0f;
    for (int k = lane; k < HID; k += 64)
        s += geluf(h[(size_t)row * HID + k]) * w2[k];
    #pragma unroll
    for (int o = 32; o; o >>= 1) s += __shfl_xor(s, o, 64);
    if (lane == 0) {
        float v = s + b2[0];
        v = (v > 0.0f) ? v : expm1f(v);
        g_pool[euOff + row] = v + 1.0f;
    }
}

// ---------------- sequential selection scan (matches jnp.cumsum order) ----------------
__global__ __launch_bounds__(256) void k_select(
    size_t euOff, size_t boundsOff, int win,
    size_t selOff, size_t tmOff, size_t euSelOff, size_t boundsNextOff)
{
    __shared__ float se[N0];
    const int* bounds = (const int*)(g_pool + boundsOff);
    int N = bounds[4];
    for (int i = threadIdx.x; i < N; i += 256) se[i] = g_pool[euOff + i];
    __syncthreads();
    if (threadIdx.x != 0) return;

    int b[5];
    for (int i = 0; i < 5; ++i) b[i] = bounds[i];

    float end_u[NBAT];
    {
        float run = 0.0f; int seg = 0;
        for (int g = 0; g < N; ++g) {
            run += se[g];
            if (g == b[seg + 1] - 1) { end_u[seg] = run; ++seg; }
        }
    }
    float sample_u[NBAT - 1];
    sample_u[0] = end_u[0];                       // reference's exact formula
    for (int i = 1; i < NBAT - 1; ++i) sample_u[i] = end_u[i + 1] - end_u[i];

    int* sel = (int*)(g_pool + selOff);
    int* tm  = (int*)(g_pool + tmOff);
    float* eus = g_pool + euSelOff;
    int* bn  = (int*)(g_pool + boundsNextOff);

    float run = 0.0f, cz = 0.0f;
    int csel = 0, csel0 = 0, cnt = 0, seg = 0;
    int ec[NBAT];
    for (int g = 0; g < N; ++g) {
        while (g >= b[seg + 1]) ++seg;
        if (g == b[seg] && seg > 0) cz += sample_u[seg - 1];
        run += se[g];
        float r2 = run - cz;
        int qp1 = g - b[seg] + 1;
        bool seld = (se[g] > r2 / (float)qp1) || (qp1 <= win);
        if (seld) { sel[cnt] = g; eus[cnt] = se[g]; ++cnt; }
        csel += seld ? 1 : 0;
        if (g == 0) csel0 = csel;
        tm[g] = csel - csel0;
        if (g == b[seg + 1] - 1) ec[seg] = csel;
    }
    bn[0] = 0; bn[1] = ec[0]; bn[2] = ec[1]; bn[3] = ec[2]; bn[4] = ec[3];
}

// ---------------- r = softmax(gelu(h)@w2 + b2); dat[i] = sum_j r[j]*window(g,j) ----------------
__global__ __launch_bounds__(256) void k_rdat(
    size_t hOff, const float* __restrict__ w2, const float* __restrict__ b2,
    size_t selOff, size_t mdevOff,
    size_t srcOff, const float* __restrict__ buf, size_t boundsOff,
    size_t datOff)
{
    int i = blockIdx.x;
    if (i >= *(const int*)(g_pool + mdevOff)) return;
    const float* h = g_pool + hOff;
    const float* src = g_pool + srcOff;
    const int* bounds = (const int*)(g_pool + boundsOff);
    const int* sel = (const int*)(g_pool + selOff);
    float* dat = g_pool + datOff;

    __shared__ float gh[HID];
    __shared__ float sv[WSZ];
    __shared__ float r[WSZ];
    int tid = threadIdx.x;
    for (int k = tid; k < HID; k += 256) gh[k] = geluf(h[(size_t)i * HID + k]);
    __syncthreads();
    if (tid < WSZ) {
        float acc = 0.0f;
        for (int k = 0; k < HID; ++k) acc += gh[k] * w2[k * WSZ + tid];
        sv[tid] = acc + b2[tid];
    }
    __syncthreads();
    if (tid == 0) {
        float m = sv[0];
        for (int t = 1; t < WSZ; ++t) m = fmaxf(m, sv[t]);
        float sum = 0.0f;
        for (int t = 0; t < WSZ; ++t) { float e = expf(sv[t] - m); r[t] = e; sum += e; }
        for (int t = 0; t < WSZ; ++t) r[t] = r[t] / sum;
    }
    __syncthreads();
    int g = sel[i];
    int b1 = bounds[1], b2i = bounds[2], b3 = bounds[3];
    int s = (g >= b1) + (g >= b2i) + (g >= b3);
    int st = (s == 0) ? 0 : ((s == 1) ? b1 : ((s == 2) ? b2i : b3));
    int qp = g - st;
    for (int f = tid; f < F; f += 256) {
        float acc = 0.0f;
        for (int j = 0; j < WSZ; ++j) {
            int sp = qp - j;
            float v = (sp >= 0) ? src[(size_t)(g - j) * F + f]
                                : buf[(size_t)(15 + sp) * F + f];
            acc = fmaf(r[j], v, acc);
        }
        dat[(size_t)i * F + f] = acc;
    }
}

// ---------------- fused attention over 48 gathered kv slots ----------------
__global__ __launch_bounds__(512) void k_attn(
    const float* __restrict__ bk, const float* __restrict__ bv)
{
    int g = blockIdx.x;
    const float* qh   = g_pool + oQH;
    const float* KH0  = g_pool + oKH0;
    const float* VH0  = g_pool + oVH0;
    const float* BH0k = g_pool + oBH0K;
    const float* BH0v = g_pool + oBH0V;
    const float* DH1k = g_pool + oDH1K;
    const float* DH1v = g_pool + oDH1V;
    const float* DH2k = g_pool + oDH2K;
    const float* DH2v = g_pool + oDH2V;
    const float* eus0 = g_pool + oEUS0;
    const float* eus1 = g_pool + oEUS1;
    const int* tm0 = (const int*)(g_pool + oTM0);
    const int* tm1 = (const int*)(g_pool + oTM1);
    const int* bounds1 = (const int*)(g_pool + oB1);
    const int* bounds2 = (const int*)(g_pool + oB2);

    __shared__ const float* sK[48];
    __shared__ const float* sV[48];
    __shared__ float sScale[48];
    __shared__ float sQ[E], sBk[E], sBv[E];
    __shared__ float sc[48][8];

    int tid = threadIdx.x;
    sQ[tid]  = qh[(size_t)g * E + tid];
    sBk[tid] = bk[tid];
    sBv[tid] = bv[tid];

    if (tid < 48) {
        int s = tid;
        const float *pK = nullptr, *pV = nullptr;
        float scl = 0.0f;
        if (s < 16) {
            int s0 = (g >= 768) + (g >= 1408) + (g >= 2112);
            const int st0[4] = {0, 768, 1408, 2112};
            int sp = (g - st0[s0]) - s;
            if (sp >= 0) { pK = KH0 + (size_t)(g - s) * E; pV = VH0 + (size_t)(g - s) * E; }
            else         { pK = BH0k + (size_t)(15 + sp) * E; pV = BH0v + (size_t)(15 + sp) * E; }
            scl = 1.0f;
        } else if (s < 32) {
            int j = s - 16;
            int i1 = tm0[g];
            int b1 = bounds1[1], b2 = bounds1[2], b3 = bounds1[3];
            int sg = (i1 >= b1) + (i1 >= b2) + (i1 >= b3);
            int st = (sg == 0) ? 0 : ((sg == 1) ? b1 : ((sg == 2) ? b2 : b3));
            int sp = (i1 - st) - j;
            if (sp >= 0) { pK = DH1k + (size_t)(i1 - j) * E; pV = DH1v + (size_t)(i1 - j) * E; scl = eus0[i1 - j]; }
        } else {
            int j = s - 32;
            int i1 = tm0[g];
            int i2 = tm1[i1];
            int b1 = bounds2[1], b2 = bounds2[2], b3 = bounds2[3];
            int sg = (i2 >= b1) + (i2 >= b2) + (i2 >= b3);
            int st = (sg == 0) ? 0 : ((sg == 1) ? b1 : ((sg == 2) ? b2 : b3));
            int sp = (i2 - st) - j;
            if (sp >= 0) { pK = DH2k + (size_t)(i2 - j) * E; pV = DH2v + (size_t)(i2 - j) * E; scl = eus1[i2 - j]; }
        }
        sK[s] = pK; sV[s] = pV; sScale[s] = scl;
    }
    __syncthreads();

    if (tid < 384) {
        int s = tid >> 3, h = tid & 7;
        const float* bp = sK[s];
        float scl = sScale[s];
        float acc = 0.0f;
        int d0 = h * 64;
        if (s < 16) {
            for (int d = 0; d < 64; ++d) acc += sQ[d0 + d] * bp[d0 + d];  // bias baked in
        } else {
            for (int d = 0; d < 64; ++d) {
                float kvv = sBk[d0 + d] + (bp ? scl * bp[d0 + d] : 0.0f);
                acc += sQ[d0 + d] * kvv;
            }
        }
        sc[s][h] = acc * 0.125f;   // / sqrt(64)
    }
    __syncthreads();

    if (tid < 8) {
        int h = tid;
        float m = sc[0][h];
        for (int s = 1; s < 48; ++s) m = fmaxf(m, sc[s][h]);
        float sum = 0.0f;
        for (int s = 0; s < 48; ++s) { float e = expf(sc[s][h] - m); sc[s][h] = e; sum += e; }
        for (int s = 0; s < 48; ++s) sc[s][h] = sc[s][h] / sum;
    }
    __syncthreads();

    {
        int d = tid, h = d >> 6;
        float acc = 0.0f;
        for (int s = 0; s < 48; ++s) {
            const float* bp = sV[s];
            float vv;
            if (s < 16) vv = bp[d];
            else        vv = sBv[d] + (bp ? sScale[s] * bp[d] : 0.0f);
            acc = fmaf(sc[s][h], vv, acc);
        }
        g_pool[oCTX + (size_t)g * E + d] = acc;
    }
}

// ---------------- y2 -> out (B, 768, E) with zero padding ----------------
__global__ __launch_bounds__(256) void k_scatter(float* __restrict__ out) {
    int idx = blockIdx.x * 256 + threadIdx.x;
    if (idx >= NBAT * MAXL * E) return;
    int d = idx & (E - 1);
    int rest = idx >> 9;
    int p = rest % MAXL, bb = rest / MAXL;
    const int st[4] = {0, 768, 1408, 2112};
    const int ln[4] = {768, 640, 704, 600};
    out[idx] = (p < ln[bb]) ? g_pool[oY2 + (size_t)(st[bb] + p) * E + d] : 0.0f;
}

// ================================================================================
extern "C" void kernel_launch(void* const* d_in, const int* in_sizes, int n_in,
                              void* d_out, int out_size, void* d_ws, size_t ws_size,
                              hipStream_t stream)
{
    (void)in_sizes; (void)n_in; (void)d_ws; (void)ws_size; (void)out_size;

    const float* x      = (const float*)d_in[0];
    const float* kv_w   = (const float*)d_in[2];
    const float* kv_b   = (const float*)d_in[3];
    const float* q_w    = (const float*)d_in[4];
    const float* q_b    = (const float*)d_in[5];
    const float* proj_w = (const float*)d_in[6];
    const float* proj_b = (const float*)d_in[7];
    const float* buf0   = (const float*)d_in[8];
    const float* buf1   = (const float*)d_in[9];
    const float* d0_w1  = (const float*)d_in[11];
    const float* d0_b1  = (const float*)d_in[12];
    const float* d0_w2  = (const float*)d_in[13];
    const float* d0_b2  = (const float*)d_in[14];
    const float* u0_w1  = (const float*)d_in[15];
    const float* u0_b1  = (const float*)d_in[16];
    const float* u0_w2  = (const float*)d_in[17];
    const float* u0_b2  = (const float*)d_in[18];
    const float* d1_w1  = (const float*)d_in[19];
    const float* d1_b1  = (const float*)d_in[20];
    const float* d1_w2  = (const float*)d_in[21];
    const float* d1_b2  = (const float*)d_in[22];
    const float* u1_w1  = (const float*)d_in[23];
    const float* u1_b1  = (const float*)d_in[24];
    const float* u1_w2  = (const float*)d_in[25];
    const float* u1_b2  = (const float*)d_in[26];
    const float* wq     = (const float*)d_in[27];
    const float* bq     = (const float*)d_in[28];
    const float* wk     = (const float*)d_in[29];
    const float* bk     = (const float*)d_in[30];
    const float* wv     = (const float*)d_in[31];
    const float* bv     = (const float*)d_in[32];
    const float* out_w  = (const float*)d_in[33];
    const float* out_b  = (const float*)d_in[34];

    auto cdiv = [](int a, int b) { return (a + b - 1) / b; };
    auto G = [&](int M, int N) { return dim3(cdiv(M, 64), cdiv(N, 64)); };
    dim3 GW(cdiv(N0, 64), cdiv(HID, 64), NSPLIT);   // 43 x 3 x 16 = 2064 blocks
    int RED = cdiv(N0 * HID, 256);

    k_init<<<1, 64, 0, stream>>>();
    k_xflat<<<cdiv(N0 * E, 256), 256, 0, stream>>>(x);

    // kv0 = x_flat @ kv_w + kv_b
    k_pgemm<<<G(N0, F), 256, 0, stream>>>(nullptr, oXF, E, kv_w, kv_b, oKV0, N0, NOFF, E, F);
    // q = x_flat @ q_w + q_b ; qh = q @ wq + bq
    k_pgemm<<<G(N0, E), 256, 0, stream>>>(nullptr, oXF, E, q_w, q_b, oQ, N0, NOFF, E, E);
    k_pgemm<<<G(N0, E), 256, 0, stream>>>(nullptr, oQ, E, wq, bq, oQH, N0, NOFF, E, E);

    // ---- level 0: u0 windowed MLP -> eu0 -> selection ----
    k_wgemm<<<GW, 256, 0, stream>>>(oKV0, buf0, NOFF, oB0, u0_w1, N0, NOFF);
    k_wreduce<<<RED, 256, 0, stream>>>(u0_b1, oHU0, NOFF, N0);
    k_eu<<<N0, 64, 0, stream>>>(oHU0, u0_w2, u0_b2, oEU0, NOFF, N0);
    k_select<<<1, 256, 0, stream>>>(oEU0, oB0, WSZ, oSEL0, oTM0, oEUS0, oB1);

    // ---- d0 windowed MLP on selected rows -> dat1 ----
    k_wgemm<<<GW, 256, 0, stream>>>(oKV0, buf0, oSEL0, oB0, d0_w1, N0, oB1 + 4);
    k_wreduce<<<RED, 256, 0, stream>>>(d0_b1, oHD0, oB1 + 4, N0);
    k_rdat<<<N0, 256, 0, stream>>>(oHD0, d0_w2, d0_b2, oSEL0, oB1 + 4, oKV0, buf0, oB0, oDAT1);

    // ---- level 1: u1 -> eu1 -> selection ----
    k_wgemm<<<GW, 256, 0, stream>>>(oDAT1, buf1, NOFF, oB1, u1_w1, N0, oB1 + 4);
    k_wreduce<<<RED, 256, 0, stream>>>(u1_b1, oHU1, oB1 + 4, N0);
    k_eu<<<N0, 64, 0, stream>>>(oHU1, u1_w2, u1_b2, oEU1, oB1 + 4, N0);
    k_select<<<1, 256, 0, stream>>>(oEU1, oB1, WSZ, oSEL1, oTM1, oEUS1, oB2);

    // ---- d1 on selected level-1 rows -> dat2 ----
    k_wgemm<<<GW, 256, 0, stream>>>(oDAT1, buf1, oSEL1, oB1, d1_w1, N0, oB2 + 4);
    k_wreduce<<<RED, 256, 0, stream>>>(d1_b1, oHD1, oB2 + 4, N0);
    k_rdat<<<N0, 256, 0, stream>>>(oHD1, d1_w2, d1_b2, oSEL1, oB2 + 4, oDAT1, buf1, oB1, oDAT2);

    // ---- attention prep: project every distinct kv row once (linearity) ----
    k_pgemm<<<G(N0, E), 256, 0, stream>>>(nullptr, oKV0, F, wk, bk, oKH0, N0, NOFF, E, E);
    k_pgemm<<<G(N0, E), 256, 0, stream>>>(nullptr, oKV0 + E, F, wv, bv, oVH0, N0, NOFF, E, E);
    k_pgemm<<<G(15, E), 256, 0, stream>>>(buf0, 0, F, wk, bk, oBH0K, 15, NOFF, E, E);
    k_pgemm<<<G(15, E), 256, 0, stream>>>(buf0 + E, 0, F, wv, bv, oBH0V, 15, NOFF, E, E);
    k_pgemm<<<G(N0, E), 256, 0, stream>>>(nullptr, oDAT1, F, wk, nullptr, oDH1K, N0, oB1 + 4, E, E);
    k_pgemm<<<G(N0, E), 256, 0, stream>>>(nullptr, oDAT1 + E, F, wv, nullptr, oDH1V, N0, oB1 + 4, E, E);
    k_pgemm<<<G(N0, E), 256, 0, stream>>>(nullptr, oDAT2, F, wk, nullptr, oDH2K, N0, oB2 + 4, E, E);
    k_pgemm<<<G(N0, E), 256, 0, stream>>>(nullptr, oDAT2 + E, F, wv, nullptr, oDH2V, N0, oB2 + 4, E, E);

    // ---- fused attention + output projections + scatter ----
    k_attn<<<N0, 512, 0, stream>>>(bk, bv);
    k_pgemm<<<G(N0, E), 256, 0, stream>>>(nullptr, oCTX, E, out_w, out_b, oY1, N0, NOFF, E, E);
    k_pgemm<<<G(N0, E), 256, 0, stream>>>(nullptr, oY1, E, proj_w, proj_b, oY2, N0, NOFF, E, E);
    k_scatter<<<cdiv(NBAT * MAXL * E, 256), 256, 0, stream>>>((float*)d_out);
}

// Round 3
// 2300.239 us; speedup vs baseline: 4.8541x; 1.4964x over previous
//
#include <hip/hip_runtime.h>
#include <cstddef>

#define DEVFN __device__ __forceinline__

constexpr int N0   = 2712;             // 768+640+704+600
constexpr int MAXL = 768;
constexpr int NBAT = 4;
constexpr int E    = 512;
constexpr int F    = 1024;
constexpr int HID  = 160;
constexpr int WSZ  = 16;               // window length
constexpr int NSPLIT = 16;             // split-K factor = window size
constexpr size_t NOFF = (size_t)-1;

// ---------------- static device scratch pool (offsets in floats) ----------------
constexpr size_t oXF   = 0;
constexpr size_t oKV0  = oXF   + (size_t)N0*E;
constexpr size_t oQ    = oKV0  + (size_t)N0*F;
constexpr size_t oQH   = oQ    + (size_t)N0*E;
constexpr size_t oHU0  = oQH   + (size_t)N0*E;
constexpr size_t oEU0  = oHU0  + (size_t)N0*HID;
constexpr size_t oHD0  = oEU0  + (size_t)N0;
constexpr size_t oDAT1 = oHD0  + (size_t)N0*HID;
constexpr size_t oHU1  = oDAT1 + (size_t)N0*F;
constexpr size_t oEU1  = oHU1  + (size_t)N0*HID;
constexpr size_t oHD1  = oEU1  + (size_t)N0;
constexpr size_t oDAT2 = oHD1  + (size_t)N0*HID;
constexpr size_t oKH0  = oDAT2 + (size_t)N0*F;
constexpr size_t oVH0  = oKH0  + (size_t)N0*E;
constexpr size_t oBH0K = oVH0  + (size_t)N0*E;
constexpr size_t oBH0V = oBH0K + (size_t)15*E;
constexpr size_t oDH1K = oBH0V + (size_t)15*E;
constexpr size_t oDH1V = oDH1K + (size_t)N0*E;
constexpr size_t oDH2K = oDH1V + (size_t)N0*E;
constexpr size_t oDH2V = oDH2K + (size_t)N0*E;
constexpr size_t oCTX  = oDH2V + (size_t)N0*E;
constexpr size_t oY1   = oCTX  + (size_t)N0*E;
constexpr size_t oY2   = oY1   + (size_t)N0*E;
constexpr size_t oEUS0 = oY2   + (size_t)N0*E;
constexpr size_t oEUS1 = oEUS0 + (size_t)N0;
constexpr size_t oSEL0 = oEUS1 + (size_t)N0;
constexpr size_t oTM0  = oSEL0 + (size_t)N0;
constexpr size_t oSEL1 = oTM0  + (size_t)N0;
constexpr size_t oTM1  = oSEL1 + (size_t)N0;
constexpr size_t oB0   = oTM1  + (size_t)N0;
constexpr size_t oB1   = oB0   + 8;
constexpr size_t oB2   = oB1   + 8;
constexpr size_t oPART = oB2   + 8;                          // split-K partials
constexpr size_t oEND  = oPART + (size_t)NSPLIT*N0*HID;

__device__ float g_pool[oEND];   // ~135 MB, allocated at module load (graph-capture safe)

DEVFN float geluf(float x) {
    return 0.5f * x * (1.0f + erff(x / 1.41421356237309504880f));
}

// ---------------- tiny init: level-0 segment bounds ----------------
__global__ void k_init() {
    if (threadIdx.x == 0) {
        int* b = (int*)(g_pool + oB0);
        b[0] = 0; b[1] = 768; b[2] = 1408; b[3] = 2112; b[4] = N0;
    }
}

// ---------------- x (B,768,E) -> x_flat (N0,E) ----------------
__global__ __launch_bounds__(256) void k_xflat(const float* __restrict__ x) {
    int idx = blockIdx.x * 256 + threadIdx.x;
    if (idx >= N0 * E) return;
    int d = idx & (E - 1);
    int g = idx >> 9;
    int s = (g >= 768) + (g >= 1408) + (g >= 2112);
    const int st[4] = {0, 768, 1408, 2112};
    int qp = g - st[s];
    g_pool[oXF + idx] = x[((size_t)s * MAXL + qp) * E + d];
}

// ---------------- plain f32 GEMM: C = A@B + bias ----------------
__global__ __launch_bounds__(256) void k_pgemm(
    const float* __restrict__ Aext, size_t Aoff, int lda,
    const float* __restrict__ B, const float* __restrict__ bias,
    size_t Coff, int M, size_t mdevOff, int K, int N)
{
    int mval = (mdevOff == NOFF) ? M : *(const int*)(g_pool + mdevOff);
    int row0 = blockIdx.x * 64, col0 = blockIdx.y * 64;
    if (row0 >= mval) return;

    const float* A = Aext ? Aext : (g_pool + Aoff);
    float* C = g_pool + Coff;

    __shared__ __align__(16) float As[32][68];
    __shared__ __align__(16) float Bs[32][64];

    int tid = threadIdx.x;
    float acc[4][4] = {};
    int tx = tid & 15, ty = tid >> 4;

    for (int k0 = 0; k0 < K; k0 += 32) {
        #pragma unroll
        for (int l = 0; l < 8; ++l) {
            int idx = tid + l * 256;
            int kk = idx & 31, m = idx >> 5;
            int r = row0 + m;
            float v = 0.0f;
            if (r < mval) v = A[(size_t)r * lda + k0 + kk];
            As[kk][m] = v;
        }
        #pragma unroll
        for (int l = 0; l < 8; ++l) {
            int idx = tid + l * 256;
            int n = idx & 63, kk = idx >> 6;
            int col = col0 + n;
            float v = 0.0f;
            if (col < N) v = B[(size_t)(k0 + kk) * N + col];
            Bs[kk][n] = v;
        }
        __syncthreads();
        #pragma unroll
        for (int kk = 0; kk < 32; ++kk) {
            float4 a4 = *(const float4*)&As[kk][ty * 4];
            float4 b4 = *(const float4*)&Bs[kk][tx * 4];
            float av[4] = {a4.x, a4.y, a4.z, a4.w};
            float bv[4] = {b4.x, b4.y, b4.z, b4.w};
            #pragma unroll
            for (int i = 0; i < 4; ++i)
                #pragma unroll
                for (int jn = 0; jn < 4; ++jn)
                    acc[i][jn] = fmaf(av[i], bv[jn], acc[i][jn]);
        }
        __syncthreads();
    }

    #pragma unroll
    for (int i = 0; i < 4; ++i) {
        int r = row0 + ty * 4 + i;
        if (r >= mval) continue;
        #pragma unroll
        for (int jn = 0; jn < 4; ++jn) {
            int col = col0 + tx * 4 + jn;
            if (col < N)
                C[(size_t)r * N + col] = acc[i][jn] + (bias ? bias[col] : 0.0f);
        }
    }
}

// ---------------- windowed GEMM, split-K over window index j ----------------
// part[z][r][n] = sum_f window(r, j=z, f) * W1[(z*F+f)][n]
__global__ __launch_bounds__(256) void k_wgemm(
    size_t srcOff, const float* __restrict__ buf, size_t rowmapOff, size_t boundsOff,
    const float* __restrict__ B, int M, size_t mdevOff)
{
    int mval = (mdevOff == NOFF) ? M : *(const int*)(g_pool + mdevOff);
    int row0 = blockIdx.x * 64, col0 = blockIdx.y * 64;
    int j = blockIdx.z;
    if (row0 >= mval) return;

    const float* src = g_pool + srcOff;
    const int* rowmap = (rowmapOff == NOFF) ? nullptr : (const int*)(g_pool + rowmapOff);
    float* part = g_pool + oPART + (size_t)j * N0 * HID;

    __shared__ __align__(16) float As[32][68];
    __shared__ __align__(16) float Bs[32][64];
    __shared__ const float* sPtr[64];

    int tid = threadIdx.x;
    if (tid < 64) {
        int r = row0 + tid;
        const float* p = src;                  // dummy-safe for r >= mval
        if (r < mval) {
            const int* bounds = (const int*)(g_pool + boundsOff);
            int g = rowmap ? rowmap[r] : r;
            int b1 = bounds[1], b2 = bounds[2], b3 = bounds[3];
            int s = (g >= b1) + (g >= b2) + (g >= b3);
            int st = (s == 0) ? 0 : ((s == 1) ? b1 : ((s == 2) ? b2 : b3));
            int sp = (g - st) - j;
            p = (sp >= 0) ? (src + (size_t)(g - j) * F)
                          : (buf + (size_t)(15 + sp) * F);
        }
        sPtr[tid] = p;
    }
    __syncthreads();

    float acc[4][4] = {};
    int tx = tid & 15, ty = tid >> 4;
    const float* Bj = B + (size_t)j * F * HID;

    for (int f0 = 0; f0 < F; f0 += 32) {
        #pragma unroll
        for (int l = 0; l < 8; ++l) {
            int idx = tid + l * 256;
            int kk = idx & 31, m = idx >> 5;
            As[kk][m] = sPtr[m][f0 + kk];
        }
        #pragma unroll
        for (int l = 0; l < 8; ++l) {
            int idx = tid + l * 256;
            int n = idx & 63, kk = idx >> 6;
            int col = col0 + n;
            float v = 0.0f;
            if (col < HID) v = Bj[(size_t)(f0 + kk) * HID + col];
            Bs[kk][n] = v;
        }
        __syncthreads();
        #pragma unroll
        for (int kk = 0; kk < 32; ++kk) {
            float4 a4 = *(const float4*)&As[kk][ty * 4];
            float4 b4 = *(const float4*)&Bs[kk][tx * 4];
            float av[4] = {a4.x, a4.y, a4.z, a4.w};
            float bv[4] = {b4.x, b4.y, b4.z, b4.w};
            #pragma unroll
            for (int i = 0; i < 4; ++i)
                #pragma unroll
                for (int jn = 0; jn < 4; ++jn)
                    acc[i][jn] = fmaf(av[i], bv[jn], acc[i][jn]);
        }
        __syncthreads();
    }

    #pragma unroll
    for (int i = 0; i < 4; ++i) {
        int r = row0 + ty * 4 + i;
        if (r >= mval) continue;
        #pragma unroll
        for (int jn = 0; jn < 4; ++jn) {
            int col = col0 + tx * 4 + jn;
            if (col < HID)
                part[(size_t)r * HID + col] = acc[i][jn];
        }
    }
}

// ---------------- reduce split-K partials (+bias), in fixed j order ----------------
__global__ __launch_bounds__(256) void k_wreduce(
    const float* __restrict__ bias, size_t outOff, size_t mdevOff, int M)
{
    int mval = (mdevOff == NOFF) ? M : *(const int*)(g_pool + mdevOff);
    int idx = blockIdx.x * 256 + threadIdx.x;
    if (idx >= mval * HID) return;
    int n = idx % HID;
    float s = bias[n];
    const float* part = g_pool + oPART;
    #pragma unroll
    for (int z = 0; z < NSPLIT; ++z)
        s += part[(size_t)z * N0 * HID + idx];
    g_pool[outOff + idx] = s;
}

// ---------------- eu = elu(gelu(h)@w2 + b2) + 1 ----------------
__global__ __launch_bounds__(64) void k_eu(
    size_t hOff, const float* __restrict__ w2, const float* __restrict__ b2,
    size_t euOff, size_t mdevOff, int M)
{
    int row = blockIdx.x;
    int mval = (mdevOff == NOFF) ? M : *(const int*)(g_pool + mdevOff);
    if (row >= mval) return;
    const float* h = g_pool + hOff;
    int lane = threadIdx.x;
    float s = 0.0f;
    for (int k = lane; k < HID; k += 64)
        s += geluf(h[(size_t)row * HID + k]) * w2[k];
    #pragma unroll
    for (int o = 32; o; o >>= 1) s += __shfl_xor(s, o, 64);
    if (lane == 0) {
        float v = s + b2[0];
        v = (v > 0.0f) ? v : expm1f(v);
        g_pool[euOff + row] = v + 1.0f;
    }
}

// ---------------- selection scan: serial f32 prefix (bit-exact) + parallel rest ----------------
__global__ __launch_bounds__(256) void k_select(
    size_t euOff, size_t boundsOff, int win,
    size_t selOff, size_t tmOff, size_t euSelOff, size_t boundsNextOff)
{
    __shared__ __align__(16) float se[N0];
    __shared__ __align__(16) float run[N0];
    __shared__ int sFlag[N0];
    __shared__ int sSum[256];
    __shared__ float sCz[NBAT];
    __shared__ int sEc[NBAT];
    __shared__ int sB[5];

    int tid = threadIdx.x;
    const int* bounds = (const int*)(g_pool + boundsOff);
    if (tid < 5) sB[tid] = bounds[tid];
    __syncthreads();
    int N = sB[4];
    for (int i = tid; i < N; i += 256) se[i] = g_pool[euOff + i];
    __syncthreads();

    // ---- Phase B: serial f32 inclusive prefix (must match numpy's summation order) ----
    if (tid == 0) {
        float r = 0.0f;
        int g = 0;
        for (; g + 8 <= N; g += 8) {
            float4 a = *(const float4*)&se[g];
            float4 b4 = *(const float4*)&se[g + 4];
            r += a.x;  run[g]     = r;
            r += a.y;  run[g + 1] = r;
            r += a.z;  run[g + 2] = r;
            r += a.w;  run[g + 3] = r;
            r += b4.x; run[g + 4] = r;
            r += b4.y; run[g + 5] = r;
            r += b4.z; run[g + 6] = r;
            r += b4.w; run[g + 7] = r;
        }
        for (; g < N; ++g) { r += se[g]; run[g] = r; }
        // end_u -> sample_u -> cz (serial order as in reference)
        float e0 = run[sB[1] - 1], e1 = run[sB[2] - 1], e2 = run[sB[3] - 1], e3 = run[sB[4] - 1];
        (void)e3;
        float su0 = e0;             // sample_u = [end_u[0], end_u[2]-end_u[1], end_u[3]-end_u[2]]
        float su1 = e2 - e1;
        float su2 = run[sB[4] - 1] - e2;
        sCz[0] = 0.0f;
        sCz[1] = su0;
        sCz[2] = su0 + su1;
        sCz[3] = (su0 + su1) + su2;
    }
    __syncthreads();

    // ---- Phase C: parallel decisions (bit-identical per-element arithmetic) ----
    for (int g = tid; g < N; g += 256) {
        int seg = (g >= sB[1]) + (g >= sB[2]) + (g >= sB[3]);
        int st = (seg == 0) ? 0 : sB[seg];
        int qp1 = g - st + 1;
        float r2 = run[g] - sCz[seg];
        bool seld = (se[g] > r2 / (float)qp1) || (qp1 <= win);
        sFlag[g] = seld ? 1 : 0;
    }
    __syncthreads();

    // ---- Phase D: integer compaction (chunked scan, exact) ----
    int CH = (N + 255) >> 8;
    int lo = tid * CH, hi = min(lo + CH, N);
    {
        int s = 0;
        for (int g = lo; g < hi; ++g) s += sFlag[g];
        sSum[tid] = s;
    }
    __syncthreads();
    if (tid == 0) {
        int acc = 0;
        for (int t = 0; t < 256; ++t) { int v = sSum[t]; sSum[t] = acc; acc += v; }
    }
    __syncthreads();

    int* sel = (int*)(g_pool + selOff);
    int* tm  = (int*)(g_pool + tmOff);
    float* eus = g_pool + euSelOff;
    int* bn  = (int*)(g_pool + boundsNextOff);

    int csel0 = sFlag[0];            // g=0 always selected (qp1=1 <= win)
    {
        int csel = sSum[tid];        // exclusive base for this chunk
        for (int g = lo; g < hi; ++g) {
            csel += sFlag[g];
            tm[g] = csel - csel0;
            if (sFlag[g]) { sel[csel - 1] = g; eus[csel - 1] = se[g]; }
            #pragma unroll
            for (int s = 0; s < NBAT; ++s)
                if (g == sB[s + 1] - 1) sEc[s] = csel;
        }
    }
    __syncthreads();
    if (tid == 0) {
        bn[0] = 0; bn[1] = sEc[0]; bn[2] = sEc[1]; bn[3] = sEc[2]; bn[4] = sEc[3];
    }
}

// ---------------- r = softmax(gelu(h)@w2 + b2); dat[i] = sum_j r[j]*window(g,j) ----------------
__global__ __launch_bounds__(256) void k_rdat(
    size_t hOff, const float* __restrict__ w2, const float* __restrict__ b2,
    size_t selOff, size_t mdevOff,
    size_t srcOff, const float* __restrict__ buf, size_t boundsOff,
    size_t datOff)
{
    int i = blockIdx.x;
    if (i >= *(const int*)(g_pool + mdevOff)) return;
    const float* h = g_pool + hOff;
    const float* src = g_pool + srcOff;
    const int* bounds = (const int*)(g_pool + boundsOff);
    const int* sel = (const int*)(g_pool + selOff);
    float* dat = g_pool + datOff;

    __shared__ float gh[HID];
    __shared__ float sv[WSZ];
    __shared__ float r[WSZ];
    int tid = threadIdx.x;
    for (int k = tid; k < HID; k += 256) gh[k] = geluf(h[(size_t)i * HID + k]);
    __syncthreads();
    if (tid < WSZ) {
        float acc = 0.0f;
        for (int k = 0; k < HID; ++k) acc += gh[k] * w2[k * WSZ + tid];
        sv[tid] = acc + b2[tid];
    }
    __syncthreads();
    if (tid == 0) {
        float m = sv[0];
        for (int t = 1; t < WSZ; ++t) m = fmaxf(m, sv[t]);
        float sum = 0.0f;
        for (int t = 0; t < WSZ; ++t) { float e = expf(sv[t] - m); r[t] = e; sum += e; }
        for (int t = 0; t < WSZ; ++t) r[t] = r[t] / sum;
    }
    __syncthreads();
    int g = sel[i];
    int b1 = bounds[1], b2i = bounds[2], b3 = bounds[3];
    int s = (g >= b1) + (g >= b2i) + (g >= b3);
    int st = (s == 0) ? 0 : ((s == 1) ? b1 : ((s == 2) ? b2i : b3));
    int qp = g - st;
    for (int f = tid; f < F; f += 256) {
        float acc = 0.0f;
        for (int j = 0; j < WSZ; ++j) {
            int sp = qp - j;
            float v = (sp >= 0) ? src[(size_t)(g - j) * F + f]
                                : buf[(size_t)(15 + sp) * F + f];
            acc = fmaf(r[j], v, acc);
        }
        dat[(size_t)i * F + f] = acc;
    }
}

// ---------------- fused attention over 48 gathered kv slots ----------------
__global__ __launch_bounds__(512) void k_attn(
    const float* __restrict__ bk, const float* __restrict__ bv)
{
    int g = blockIdx.x;
    const float* qh   = g_pool + oQH;
    const float* KH0  = g_pool + oKH0;
    const float* VH0  = g_pool + oVH0;
    const float* BH0k = g_pool + oBH0K;
    const float* BH0v = g_pool + oBH0V;
    const float* DH1k = g_pool + oDH1K;
    const float* DH1v = g_pool + oDH1V;
    const float* DH2k = g_pool + oDH2K;
    const float* DH2v = g_pool + oDH2V;
    const float* eus0 = g_pool + oEUS0;
    const float* eus1 = g_pool + oEUS1;
    const int* tm0 = (const int*)(g_pool + oTM0);
    const int* tm1 = (const int*)(g_pool + oTM1);
    const int* bounds1 = (const int*)(g_pool + oB1);
    const int* bounds2 = (const int*)(g_pool + oB2);

    __shared__ const float* sK[48];
    __shared__ const float* sV[48];
    __shared__ float sScale[48];
    __shared__ float sQ[E], sBk[E], sBv[E];
    __shared__ float sc[48][8];

    int tid = threadIdx.x;
    sQ[tid]  = qh[(size_t)g * E + tid];
    sBk[tid] = bk[tid];
    sBv[tid] = bv[tid];

    if (tid < 48) {
        int s = tid;
        const float *pK = nullptr, *pV = nullptr;
        float scl = 0.0f;
        if (s < 16) {
            int s0 = (g >= 768) + (g >= 1408) + (g >= 2112);
            const int st0[4] = {0, 768, 1408, 2112};
            int sp = (g - st0[s0]) - s;
            if (sp >= 0) { pK = KH0 + (size_t)(g - s) * E; pV = VH0 + (size_t)(g - s) * E; }
            else         { pK = BH0k + (size_t)(15 + sp) * E; pV = BH0v + (size_t)(15 + sp) * E; }
            scl = 1.0f;
        } else if (s < 32) {
            int j = s - 16;
            int i1 = tm0[g];
            int b1 = bounds1[1], b2 = bounds1[2], b3 = bounds1[3];
            int sg = (i1 >= b1) + (i1 >= b2) + (i1 >= b3);
            int st = (sg == 0) ? 0 : ((sg == 1) ? b1 : ((sg == 2) ? b2 : b3));
            int sp = (i1 - st) - j;
            if (sp >= 0) { pK = DH1k + (size_t)(i1 - j) * E; pV = DH1v + (size_t)(i1 - j) * E; scl = eus0[i1 - j]; }
        } else {
            int j = s - 32;
            int i1 = tm0[g];
            int i2 = tm1[i1];
            int b1 = bounds2[1], b2 = bounds2[2], b3 = bounds2[3];
            int sg = (i2 >= b1) + (i2 >= b2) + (i2 >= b3);
            int st = (sg == 0) ? 0 : ((sg == 1) ? b1 : ((sg == 2) ? b2 : b3));
            int sp = (i2 - st) - j;
            if (sp >= 0) { pK = DH2k + (size_t)(i2 - j) * E; pV = DH2v + (size_t)(i2 - j) * E; scl = eus1[i2 - j]; }
        }
        sK[s] = pK; sV[s] = pV; sScale[s] = scl;
    }
    __syncthreads();

    if (tid < 384) {
        int s = tid >> 3, h = tid & 7;
        const float* bp = sK[s];
        float scl = sScale[s];
        float acc = 0.0f;
        int d0 = h * 64;
        if (s < 16) {
            for (int d = 0; d < 64; ++d) acc += sQ[d0 + d] * bp[d0 + d];  // bias baked in
        } else {
            for (int d = 0; d < 64; ++d) {
                float kvv = sBk[d0 + d] + (bp ? scl * bp[d0 + d] : 0.0f);
                acc += sQ[d0 + d] * kvv;
            }
        }
        sc[s][h] = acc * 0.125f;   // / sqrt(64)
    }
    __syncthreads();

    if (tid < 8) {
        int h = tid;
        float m = sc[0][h];
        for (int s = 1; s < 48; ++s) m = fmaxf(m, sc[s][h]);
        float sum = 0.0f;
        for (int s = 0; s < 48; ++s) { float e = expf(sc[s][h] - m); sc[s][h] = e; sum += e; }
        for (int s = 0; s < 48; ++s) sc[s][h] = sc[s][h] / sum;
    }
    __syncthreads();

    {
        int d = tid, h = d >> 6;
        float acc = 0.0f;
        for (int s = 0; s < 48; ++s) {
            const float* bp = sV[s];
            float vv;
            if (s < 16) vv = bp[d];
            else        vv = sBv[d] + (bp ? sScale[s] * bp[d] : 0.0f);
            acc = fmaf(sc[s][h], vv, acc);
        }
        g_pool[oCTX + (size_t)g * E + d] = acc;
    }
}

// ---------------- y2 -> out (B, 768, E) with zero padding ----------------
__global__ __launch_bounds__(256) void k_scatter(float* __restrict__ out) {
    int idx = blockIdx.x * 256 + threadIdx.x;
    if (idx >= NBAT * MAXL * E) return;
    int d = idx & (E - 1);
    int rest = idx >> 9;
    int p = rest % MAXL, bb = rest / MAXL;
    const int st[4] = {0, 768, 1408, 2112};
    const int ln[4] = {768, 640, 704, 600};
    out[idx] = (p < ln[bb]) ? g_pool[oY2 + (size_t)(st[bb] + p) * E + d] : 0.0f;
}

// ================================================================================
extern "C" void kernel_launch(void* const* d_in, const int* in_sizes, int n_in,
                              void* d_out, int out_size, void* d_ws, size_t ws_size,
                              hipStream_t stream)
{
    (void)in_sizes; (void)n_in; (void)d_ws; (void)ws_size; (void)out_size;

    const float* x      = (const float*)d_in[0];
    const float* kv_w   = (const float*)d_in[2];
    const float* kv_b   = (const float*)d_in[3];
    const float* q_w    = (const float*)d_in[4];
    const float* q_b    = (const float*)d_in[5];
    const float* proj_w = (const float*)d_in[6];
    const float* proj_b = (const float*)d_in[7];
    const float* buf0   = (const float*)d_in[8];
    const float* buf1   = (const float*)d_in[9];
    const float* d0_w1  = (const float*)d_in[11];
    const float* d0_b1  = (const float*)d_in[12];
    const float* d0_w2  = (const float*)d_in[13];
    const float* d0_b2  = (const float*)d_in[14];
    const float* u0_w1  = (const float*)d_in[15];
    const float* u0_b1  = (const float*)d_in[16];
    const float* u0_w2  = (const float*)d_in[17];
    const float* u0_b2  = (const float*)d_in[18];
    const float* d1_w1  = (const float*)d_in[19];
    const float* d1_b1  = (const float*)d_in[20];
    const float* d1_w2  = (const float*)d_in[21];
    const float* d1_b2  = (const float*)d_in[22];
    const float* u1_w1  = (const float*)d_in[23];
    const float* u1_b1  = (const float*)d_in[24];
    const float* u1_w2  = (const float*)d_in[25];
    const float* u1_b2  = (const float*)d_in[26];
    const float* wq     = (const float*)d_in[27];
    const float* bq     = (const float*)d_in[28];
    const float* wk     = (const float*)d_in[29];
    const float* bk     = (const float*)d_in[30];
    const float* wv     = (const float*)d_in[31];
    const float* bv     = (const float*)d_in[32];
    const float* out_w  = (const float*)d_in[33];
    const float* out_b  = (const float*)d_in[34];

    auto cdiv = [](int a, int b) { return (a + b - 1) / b; };
    auto G = [&](int M, int N) { return dim3(cdiv(M, 64), cdiv(N, 64)); };
    dim3 GW(cdiv(N0, 64), cdiv(HID, 64), NSPLIT);   // 43 x 3 x 16 = 2064 blocks
    int RED = cdiv(N0 * HID, 256);

    k_init<<<1, 64, 0, stream>>>();
    k_xflat<<<cdiv(N0 * E, 256), 256, 0, stream>>>(x);

    // kv0 = x_flat @ kv_w + kv_b
    k_pgemm<<<G(N0, F), 256, 0, stream>>>(nullptr, oXF, E, kv_w, kv_b, oKV0, N0, NOFF, E, F);
    // q = x_flat @ q_w + q_b ; qh = q @ wq + bq
    k_pgemm<<<G(N0, E), 256, 0, stream>>>(nullptr, oXF, E, q_w, q_b, oQ, N0, NOFF, E, E);
    k_pgemm<<<G(N0, E), 256, 0, stream>>>(nullptr, oQ, E, wq, bq, oQH, N0, NOFF, E, E);

    // ---- level 0: u0 windowed MLP -> eu0 -> selection ----
    k_wgemm<<<GW, 256, 0, stream>>>(oKV0, buf0, NOFF, oB0, u0_w1, N0, NOFF);
    k_wreduce<<<RED, 256, 0, stream>>>(u0_b1, oHU0, NOFF, N0);
    k_eu<<<N0, 64, 0, stream>>>(oHU0, u0_w2, u0_b2, oEU0, NOFF, N0);
    k_select<<<1, 256, 0, stream>>>(oEU0, oB0, WSZ, oSEL0, oTM0, oEUS0, oB1);

    // ---- d0 windowed MLP on selected rows -> dat1 ----
    k_wgemm<<<GW, 256, 0, stream>>>(oKV0, buf0, oSEL0, oB0, d0_w1, N0, oB1 + 4);
    k_wreduce<<<RED, 256, 0, stream>>>(d0_b1, oHD0, oB1 + 4, N0);
    k_rdat<<<N0, 256, 0, stream>>>(oHD0, d0_w2, d0_b2, oSEL0, oB1 + 4, oKV0, buf0, oB0, oDAT1);

    // ---- level 1: u1 -> eu1 -> selection ----
    k_wgemm<<<GW, 256, 0, stream>>>(oDAT1, buf1, NOFF, oB1, u1_w1, N0, oB1 + 4);
    k_wreduce<<<RED, 256, 0, stream>>>(u1_b1, oHU1, oB1 + 4, N0);
    k_eu<<<N0, 64, 0, stream>>>(oHU1, u1_w2, u1_b2, oEU1, oB1 + 4, N0);
    k_select<<<1, 256, 0, stream>>>(oEU1, oB1, WSZ, oSEL1, oTM1, oEUS1, oB2);

    // ---- d1 on selected level-1 rows -> dat2 ----
    k_wgemm<<<GW, 256, 0, stream>>>(oDAT1, buf1, oSEL1, oB1, d1_w1, N0, oB2 + 4);
    k_wreduce<<<RED, 256, 0, stream>>>(d1_b1, oHD1, oB2 + 4, N0);
    k_rdat<<<N0, 256, 0, stream>>>(oHD1, d1_w2, d1_b2, oSEL1, oB2 + 4, oDAT1, buf1, oB1, oDAT2);

    // ---- attention prep: project every distinct kv row once (linearity) ----
    k_pgemm<<<G(N0, E), 256, 0, stream>>>(nullptr, oKV0, F, wk, bk, oKH0, N0, NOFF, E, E);
    k_pgemm<<<G(N0, E), 256, 0, stream>>>(nullptr, oKV0 + E, F, wv, bv, oVH0, N0, NOFF, E, E);
    k_pgemm<<<G(15, E), 256, 0, stream>>>(buf0, 0, F, wk, bk, oBH0K, 15, NOFF, E, E);
    k_pgemm<<<G(15, E), 256, 0, stream>>>(buf0 + E, 0, F, wv, bv, oBH0V, 15, NOFF, E, E);
    k_pgemm<<<G(N0, E), 256, 0, stream>>>(nullptr, oDAT1, F, wk, nullptr, oDH1K, N0, oB1 + 4, E, E);
    k_pgemm<<<G(N0, E), 256, 0, stream>>>(nullptr, oDAT1 + E, F, wv, nullptr, oDH1V, N0, oB1 + 4, E, E);
    k_pgemm<<<G(N0, E), 256, 0, stream>>>(nullptr, oDAT2, F, wk, nullptr, oDH2K, N0, oB2 + 4, E, E);
    k_pgemm<<<G(N0, E), 256, 0, stream>>>(nullptr, oDAT2 + E, F, wv, nullptr, oDH2V, N0, oB2 + 4, E, E);

    // ---- fused attention + output projections + scatter ----
    k_attn<<<N0, 512, 0, stream>>>(bk, bv);
    k_pgemm<<<G(N0, E), 256, 0, stream>>>(nullptr, oCTX, E, out_w, out_b, oY1, N0, NOFF, E, E);
    k_pgemm<<<G(N0, E), 256, 0, stream>>>(nullptr, oY1, E, proj_w, proj_b, oY2, N0, NOFF, E, E);
    k_scatter<<<cdiv(NBAT * MAXL * E, 256), 256, 0, stream>>>((float*)d_out);
}